// Round 13
// baseline (579.874 us; speedup 1.0000x reference)
//
#include <hip/hip_runtime.h>
#include <type_traits>

#define NIN 784
#define BANKS 64
#define NLAYER 15
#define FAN 8
#define DD 10
#define NBF 640             // features per sample per layer
#define NSW 4               // samples per group
#define NSB 8               // samples per block (2 groups x 4)

typedef float f32x2 __attribute__((ext_vector_type(2)));

__device__ __forceinline__ float f4c_rt(const float4& v, int c) {
    return c == 0 ? v.x : (c == 1 ? v.y : (c == 2 ? v.z : v.w));
}

typedef const __attribute__((address_space(1))) void gas_void;
typedef __attribute__((address_space(3))) void las_void;

__device__ __forceinline__ void gll16(const void* g, void* l) {
    __builtin_amdgcn_global_load_lds((gas_void*)g, (las_void*)l, 16, 0, 0);
}

// chunk_t[l][k][r=0..27][bank] float4 (r<25: Wd quads; 25-27: Wg zero-padded)
// bias_t[l][q][bank] float4 = bg[l][bank][4q..4q+3]
#define NCH (NLAYER*FAN*28*64)   // 215040
#define NBI (NLAYER*2*64)        // 1920
#define GEMM_BLKS 640            // 64 M-tiles x 10 N-tiles (64x64)
#define TR_BLKS   848            // ceil((NCH+NBI)/256)

// ---------------- Fused prologue: input GEMM + weight transpose + nopen zero ----------------
__global__ __launch_bounds__(256)
void fused_prologue(const float* __restrict__ x, const float* __restrict__ Wi,
                    const float* __restrict__ bi,
                    const float* __restrict__ Wg, const float* __restrict__ bg,
                    const float* __restrict__ Wd,
                    float* __restrict__ acts,
                    float4* __restrict__ chunk_t, float4* __restrict__ bias_t,
                    unsigned int* __restrict__ nopen)
{
    if (blockIdx.x >= GEMM_BLKS) {
        if (blockIdx.x == GEMM_BLKS && threadIdx.x == 0 && nopen) *nopen = 0u;
        int tid = (blockIdx.x - GEMM_BLKS) * 256 + threadIdx.x;
        if (tid < NCH) {
            int b = tid & 63;
            int rk = tid >> 6;
            int r = rk % 28;
            int lk = rk / 28;           // l*8+k
            int k = lk & 7;
            int l = lk >> 3;
            float4 v;
            if (r < 25) {
                v = ((const float4*)Wd)[(((size_t)(l*64+b)*8 + k)*25) + r];
            } else {
                int q = r - 25;
                size_t base = ((size_t)(l*64+b)*8 + k)*10 + 4*q;
                float t[4];
#pragma unroll
                for (int c = 0; c < 4; ++c)
                    t[c] = (4*q + c < 10) ? Wg[base + c] : 0.f;
                v = make_float4(t[0], t[1], t[2], t[3]);
            }
            chunk_t[tid] = v;
        } else if (tid < NCH + NBI) {
            int t2 = tid - NCH;
            int b = t2 & 63;
            int q = (t2 >> 6) & 1;
            int l = t2 >> 7;
            bias_t[t2] = ((const float4*)bg)[(size_t)(l*64+b)*2 + q];
        }
        return;
    }

    // ---- GEMM part: 64x64 tile, 256 threads, 4x4 per thread ----
    __shared__ float As[16][68];
    __shared__ float Bs[16][68];
    const int tid = threadIdx.x;
    const int tx = tid & 15, ty = tid >> 4;
    const int m0 = (blockIdx.x & 63) * 64;
    const int n0 = (blockIdx.x >> 6) * 64;

    float acc[4][4];
#pragma unroll
    for (int i = 0; i < 4; ++i)
#pragma unroll
        for (int j = 0; j < 4; ++j) acc[i][j] = 0.f;

    for (int kb = 0; kb < NIN / 16; ++kb) {
        {
            int m = tid >> 2, kq = tid & 3;
            float4 v = *(const float4*)(x + (m0 + m) * NIN + kb * 16 + kq * 4);
            As[kq*4+0][m] = v.x; As[kq*4+1][m] = v.y;
            As[kq*4+2][m] = v.z; As[kq*4+3][m] = v.w;
            float4 u = *(const float4*)(Wi + (n0 + m) * NIN + kb * 16 + kq * 4);
            Bs[kq*4+0][m] = u.x; Bs[kq*4+1][m] = u.y;
            Bs[kq*4+2][m] = u.z; Bs[kq*4+3][m] = u.w;
        }
        __syncthreads();
#pragma unroll
        for (int k = 0; k < 16; ++k) {
            float4 a4 = *(const float4*)(&As[k][ty*4]);
            float4 b4 = *(const float4*)(&Bs[k][tx*4]);
            float av[4] = {a4.x, a4.y, a4.z, a4.w};
            float bv[4] = {b4.x, b4.y, b4.z, b4.w};
#pragma unroll
            for (int i = 0; i < 4; ++i)
#pragma unroll
                for (int j = 0; j < 4; ++j)
                    acc[i][j] = fmaf(av[i], bv[j], acc[i][j]);
        }
        __syncthreads();
    }
    float4 bv = *(const float4*)(bi + n0 + tx*4);
#pragma unroll
    for (int i = 0; i < 4; ++i) {
        int row = m0 + ty*4 + i;
        float4 o;
        o.x = fmaxf(acc[i][0] + bv.x, 0.f);
        o.y = fmaxf(acc[i][1] + bv.y, 0.f);
        o.z = fmaxf(acc[i][2] + bv.z, 0.f);
        o.w = fmaxf(acc[i][3] + bv.w, 0.f);
        *(float4*)(acts + row * NBF + n0 + tx*4) = o;
    }
}

// ---------------- Kernel B (v13): 8 waves, 4-way el-split, compile-time Q ----------------
// Block = 512 thr: wave w -> group g=w&1 (4 samples), quarter Q=w>>1.
// Q owns els {0-2,3-5,6-7,8-9}; reads only its Wd quads + 3 gate quads.
// Staging: waves 0-6 stage 4 rows each (uniform vmcnt(4)); wave 7 none (its
// barrier arrival is ordered after other waves' vmcnt -> data visible).
// Bias in registers (prefetched per layer). One exchange barrier per layer.
// LDS 77824 B -> 2 blocks/CU = 4 waves/SIMD.
__global__ __launch_bounds__(512, 4)
void routenet_v13(const float* __restrict__ acts0,
                  const float4* __restrict__ chunk_t, const float4* __restrict__ bias_t,
                  const float* __restrict__ Wo,
                  float* __restrict__ out, unsigned int* __restrict__ nopen_g)
{
    __shared__ float4 wdstage[2][28][64];   // 57344 B
    __shared__ float  exch[2][NSW][DD][64]; // 20480 B [g][s][el][bank]

    const int tid  = threadIdx.x;
    const int lane = tid & 63;
    const int w    = tid >> 6;
    const int g    = w & 1;
    const int Q    = w >> 1;
    const int b0   = blockIdx.x * NSB + g * NSW;

    // packed activations: A2[p][d] = {a(2p)[d], a(2p+1)[d]}
    f32x2 A2[2][DD];
#pragma unroll
    for (int p = 0; p < 2; ++p) {
        const float2* q0 = (const float2*)(acts0 + (size_t)(b0 + 2*p    ) * NBF + lane * DD);
        const float2* q1 = (const float2*)(acts0 + (size_t)(b0 + 2*p + 1) * NBF + lane * DD);
#pragma unroll
        for (int d2 = 0; d2 < 5; ++d2) {
            float2 v0 = q0[d2], v1 = q1[d2];
            A2[p][2*d2  ] = f32x2{v0.x, v1.x};
            A2[p][2*d2+1] = f32x2{v0.y, v1.y};
        }
    }

    f32x2 gs2[2] = { f32x2{0.f,0.f}, f32x2{0.f,0.f} };
    unsigned int nop = 0;

    auto stage_chunk = [&](int l, int k, int pdst) {
        if (w < 7) {
            const float4* base = chunk_t + (size_t)(l*8 + k) * 28 * 64;
#pragma unroll
            for (int j = 0; j < 4; ++j)
                gll16(base + (4*w + j)*64 + lane, &wdstage[pdst][4*w + j][0]);
        }
    };

    stage_chunk(0, 0, 0);
    float4 bq0 = bias_t[lane];
    float4 bq1 = bias_t[64 + lane];
    asm volatile("s_waitcnt vmcnt(0)" ::: "memory");
    asm volatile("s_barrier" ::: "memory");

    f32x2 acc2[2][3];   // [pp][local el]; Q2/Q3 use only [0..1]

    for (int l = 0; l < NLAYER; ++l) {
        float4 bn0 = bq0, bn1 = bq1;
        if (l + 1 < NLAYER) {
            bn0 = bias_t[(size_t)((l+1)*2    ) * 64 + lane];
            bn1 = bias_t[(size_t)((l+1)*2 + 1) * 64 + lane];
        }

#pragma unroll
        for (int p = 0; p < 2; ++p)
#pragma unroll
            for (int e = 0; e < 3; ++e) acc2[p][e] = f32x2{0.f, 0.f};

        auto chunk_body = [&](auto Qc, int k, int p) {
            constexpr int QQ  = Qc.value;
            constexpr int EL0 = (QQ==0) ? 0 : (QQ==1) ? 3 : (QQ==2) ? 6 : 8;
            constexpr int NEL = (QQ < 2) ? 3 : 2;
            constexpr int QD0 = (QQ==0) ? 0 : (QQ==1) ? 7 : (QQ==2) ? 15 : 20;
            constexpr int NQ  = (QQ < 2) ? 8 : 5;

            float4 wgq[3];
#pragma unroll
            for (int q = 0; q < 3; ++q) wgq[q] = wdstage[p][25 + q][lane];
            const float bias = f4c_rt((k & 4) ? bq1 : bq0, k & 3);
            float wgv[DD];
#pragma unroll
            for (int d = 0; d < DD; ++d) wgv[d] = f4c_rt(wgq[d >> 2], d & 3);

            f32x2 gz[2];
#pragma unroll
            for (int pp = 0; pp < 2; ++pp) {
                f32x2 z = f32x2{bias, bias};
#pragma unroll
                for (int d = 0; d < DD; ++d)
                    z = __builtin_elementwise_fma(A2[pp][d], f32x2{wgv[d], wgv[d]}, z);
                f32x2 gate = __builtin_elementwise_min(
                                 __builtin_elementwise_max(z, f32x2{0.f, 0.f}),
                                 f32x2{1.f, 1.f});
                if (QQ == 0) {
                    gs2[pp] += gate;
                    nop += (z[0] > 0.f) ? 1u : 0u;
                    nop += (z[1] > 0.f) ? 1u : 0u;
                }
                gz[pp] = gate;
            }

            float4 wv[NQ];
#pragma unroll
            for (int i = 0; i < NQ; ++i) wv[i] = wdstage[p][QD0 + i][lane];

            const int src = (lane - k) & 63;
#pragma unroll
            for (int e = 0; e < NEL; ++e) {
                constexpr int dummy = 0; (void)dummy;
#pragma unroll
                for (int pp = 0; pp < 2; ++pp) {
                    f32x2 dot = f32x2{0.f, 0.f};
#pragma unroll
                    for (int d = 0; d < DD; ++d) {
                        const int idx = (EL0 + e) * 10 + d;
                        const float wd = f4c_rt(wv[idx/4 - QD0], idx & 3);
                        dot = __builtin_elementwise_fma(A2[pp][d], f32x2{wd, wd}, dot);
                    }
                    f32x2 cc = gz[pp] * dot;
                    f32x2 r;
                    r[0] = __shfl(cc[0], src, 64);
                    r[1] = __shfl(cc[1], src, 64);
                    acc2[pp][e] += r;
                }
            }
        };

#pragma unroll
        for (int c = 0; c < 8; ++c) {
            const int p = c & 1;
            if (c < 7) {
                stage_chunk(l, c + 1, p ^ 1);
                asm volatile("s_waitcnt vmcnt(4)" ::: "memory");
            } else if (l + 1 < NLAYER) {
                stage_chunk(l + 1, 0, p ^ 1);
                asm volatile("s_waitcnt vmcnt(4)" ::: "memory");
            } else {
                asm volatile("s_waitcnt vmcnt(0)" ::: "memory");
            }
            asm volatile("s_barrier" ::: "memory");

            if      (Q == 0) chunk_body(std::integral_constant<int,0>{}, c, p);
            else if (Q == 1) chunk_body(std::integral_constant<int,1>{}, c, p);
            else if (Q == 2) chunk_body(std::integral_constant<int,2>{}, c, p);
            else             chunk_body(std::integral_constant<int,3>{}, c, p);

            if (c < 7) {
                asm volatile("s_waitcnt lgkmcnt(0)" ::: "memory");
                asm volatile("s_barrier" ::: "memory");
            }
        }

        // layer end: ReLU + publish own els (compile-time Q), one barrier, read others
        auto publish = [&](auto Qc) {
            constexpr int QQ  = Qc.value;
            constexpr int EL0 = (QQ==0) ? 0 : (QQ==1) ? 3 : (QQ==2) ? 6 : 8;
            constexpr int NEL = (QQ < 2) ? 3 : 2;
#pragma unroll
            for (int s = 0; s < NSW; ++s)
#pragma unroll
                for (int e = 0; e < NEL; ++e) {
                    float v = fmaxf(acc2[s>>1][e][s&1], 0.f);
                    A2[s>>1][EL0 + e][s&1] = v;
                    exch[g][s][EL0 + e][lane] = v;
                }
        };
        auto readback = [&](auto Qc) {
            constexpr int QQ  = Qc.value;
            constexpr int EL0 = (QQ==0) ? 0 : (QQ==1) ? 3 : (QQ==2) ? 6 : 8;
            constexpr int NEL = (QQ < 2) ? 3 : 2;
#pragma unroll
            for (int el = 0; el < DD; ++el) {
                if (el < EL0 || el >= EL0 + NEL) {
#pragma unroll
                    for (int s = 0; s < NSW; ++s)
                        A2[s>>1][el][s&1] = exch[g][s][el][lane];
                }
            }
        };

        if      (Q == 0) publish(std::integral_constant<int,0>{});
        else if (Q == 1) publish(std::integral_constant<int,1>{});
        else if (Q == 2) publish(std::integral_constant<int,2>{});
        else             publish(std::integral_constant<int,3>{});

        asm volatile("s_waitcnt lgkmcnt(0)" ::: "memory");
        asm volatile("s_barrier" ::: "memory");   // also serves as c==7 trailing

        if      (Q == 0) readback(std::integral_constant<int,0>{});
        else if (Q == 1) readback(std::integral_constant<int,1>{});
        else if (Q == 2) readback(std::integral_constant<int,2>{});
        else             readback(std::integral_constant<int,3>{});
        // next write to exch is >=16 barriers away -> single buffer safe

        bq0 = bn0; bq1 = bn1;
    }

    // epilogue: Q==0 waves (one per group) have full activations
    if (Q == 0) {
        float wo[DD];
        const float2* pw = (const float2*)(Wo + lane * DD);
#pragma unroll
        for (int d2 = 0; d2 < 5; ++d2) {
            float2 v = pw[d2];
            wo[2*d2] = v.x; wo[2*d2+1] = v.y;
        }
#pragma unroll
        for (int p = 0; p < 2; ++p) {
            f32x2 o = f32x2{0.f, 0.f};
#pragma unroll
            for (int d = 0; d < DD; ++d)
                o = __builtin_elementwise_fma(A2[p][d], f32x2{wo[d], wo[d]}, o);
            out[(size_t)(b0 + 2*p    ) * BANKS + lane] = fmaxf(o[0], 0.f);
            out[(size_t)(b0 + 2*p + 1) * BANKS + lane] = fmaxf(o[1], 0.f);
        }

#pragma unroll
        for (int s = 0; s < NSW; ++s) {
            float v = gs2[s>>1][s&1];
#pragma unroll
            for (int off = 32; off; off >>= 1) v += __shfl_xor(v, off, 64);
            if (lane == 0)
                out[(size_t)4096 * BANKS + b0 + s] = v * (1.0f / 7680.0f);
        }
        {
            unsigned int v = nop;
#pragma unroll
            for (int off = 32; off; off >>= 1) v += __shfl_xor(v, off, 64);
            if (lane == 0) atomicAdd(nopen_g, v);
        }
    }
}

// ---------------- Fallback kernel (no-workspace path): v5-style LDS staging ----------------
__global__ __launch_bounds__(256, 2)
void routenet_v5f(const float* __restrict__ acts0,
                  const float* __restrict__ x, const float* __restrict__ Wi,
                  const float* __restrict__ bi,
                  const float* __restrict__ Wg, const float* __restrict__ bg,
                  const float* __restrict__ Wd, const float* __restrict__ Wo,
                  float* __restrict__ out, unsigned int* __restrict__ nopen_g)
{
    __shared__ float4 wdstage[2][28][64];
    __shared__ float4 biasbuf[2][2][64];
    __shared__ float  exch[2][4][5][64];

    const int tid  = threadIdx.x;
    const int lane = tid & 63;
    const int w    = tid >> 6;
    const int g    = w & 1;
    const int h    = w >> 1;
    const int b0   = blockIdx.x * NSB + g * 4;

    float a[4][DD];

    if (acts0) {
#pragma unroll
        for (int s = 0; s < 4; ++s) {
            const float2* p = (const float2*)(acts0 + (size_t)(b0 + s) * NBF + lane * DD);
#pragma unroll
            for (int d2 = 0; d2 < 5; ++d2) {
                float2 v = p[d2];
                a[s][d2*2]   = v.x;
                a[s][d2*2+1] = v.y;
            }
        }
    } else {
        for (int s = 0; s < 4; ++s) {
            const float* xb2 = x + (size_t)(b0 + s) * NIN;
            for (int d = 0; d < DD; ++d) {
                int n = lane * DD + d;
                const float* wr = Wi + (size_t)n * NIN;
                float z = bi[n];
                for (int i = 0; i < NIN; ++i) z = fmaf(xb2[i], wr[i], z);
                a[s][d] = fmaxf(z, 0.f);
            }
        }
    }

    float gsum[4];
#pragma unroll
    for (int s = 0; s < 4; ++s) gsum[s] = 0.f;
    unsigned int nop = 0;

    auto stage_chunk = [&](int l, int k, int pdst) {
        const float* wd_base = Wd + (size_t)l * (BANKS*FAN*DD*DD)
                                  + (size_t)lane * (FAN*DD*DD) + k * (DD*DD);
        const float* wg_base = Wg + (size_t)l * (BANKS*FAN*DD)
                                  + lane * (FAN*DD) + ((10*k) >> 2) * 4;
#pragma unroll
        for (int j = 0; j < 7; ++j) {
            int r = w + 4 * j;
            if (r < 25) gll16(wd_base + r * 4, &wdstage[pdst][r][0]);
            else        gll16(wg_base + (r - 25) * 4, &wdstage[pdst][r][0]);
        }
    };
    auto stage_bias = [&](int l) {
        int q = w & 1;
        gll16(bg + (size_t)l * (BANKS*FAN) + lane * FAN + q * 4,
              &biasbuf[l & 1][q][0]);
    };

    stage_chunk(0, 0, 0);
    stage_bias(0);
    asm volatile("s_waitcnt vmcnt(0)" ::: "memory");
    asm volatile("s_barrier" ::: "memory");

    for (int l = 0; l < NLAYER; ++l) {
        const int lp = l & 1;
        float acc[4][5];
#pragma unroll
        for (int s = 0; s < 4; ++s)
#pragma unroll
            for (int el = 0; el < 5; ++el) acc[s][el] = 0.f;

        auto chunk_body = [&](auto Hc, int k, int p) {
            constexpr int H = Hc.value;
            float4 wgq[3];
#pragma unroll
            for (int q = 0; q < 3; ++q) wgq[q] = wdstage[p][25 + q][lane];
            const float bias = f4c_rt(biasbuf[lp][(k >> 2) & 1][lane], k & 3);
            float wgv[DD];
            if ((k & 1) == 0) {
#pragma unroll
                for (int d = 0; d < DD; ++d) wgv[d] = f4c_rt(wgq[d >> 2], d & 3);
            } else {
#pragma unroll
                for (int d = 0; d < DD; ++d) wgv[d] = f4c_rt(wgq[(d+2) >> 2], (d+2) & 3);
            }

            float gz[4];
#pragma unroll
            for (int s = 0; s < 4; ++s) {
                float z = bias;
#pragma unroll
                for (int d = 0; d < DD; ++d) z = fmaf(a[s][d], wgv[d], z);
                float gate = fminf(fmaxf(z, 0.f), 1.f);
                if (H == 0) { gsum[s] += gate; nop += (z > 0.f) ? 1u : 0u; }
                gz[s] = gate;
            }

            float4 wv[13];
#pragma unroll
            for (int i = 0; i < 13; ++i) wv[i] = wdstage[p][12*H + i][lane];

            const int src = (lane - k) & 63;
#pragma unroll
            for (int el = 0; el < 5; ++el) {
#pragma unroll
                for (int s = 0; s < 4; ++s) {
                    float dot = 0.f;
#pragma unroll
                    for (int d = 0; d < DD; ++d) {
                        const int idx = (5*H + el) * 10 + d - 48*H;
                        dot = fmaf(a[s][d], f4c_rt(wv[idx >> 2], idx & 3), dot);
                    }
                    acc[s][el] += __shfl(gz[s] * dot, src, 64);
                }
            }
        };

#pragma unroll
        for (int c = 0; c < 8; ++c) {
            const int p = c & 1;
            if (c < 7) {
                stage_chunk(l, c + 1, p ^ 1);
                asm volatile("s_waitcnt vmcnt(7)" ::: "memory");
            } else if (l + 1 < NLAYER) {
                stage_chunk(l + 1, 0, p ^ 1);
                stage_bias(l + 1);
                asm volatile("s_waitcnt vmcnt(8)" ::: "memory");
            } else {
                asm volatile("s_waitcnt vmcnt(0)" ::: "memory");
            }
            asm volatile("s_barrier" ::: "memory");

            if (h == 0) chunk_body(std::integral_constant<int,0>{}, c, p);
            else        chunk_body(std::integral_constant<int,1>{}, c, p);

            if (c < 7) {
                asm volatile("s_waitcnt lgkmcnt(0)" ::: "memory");
                asm volatile("s_barrier" ::: "memory");
            }
        }

        if (h == 0) {
#pragma unroll
            for (int s = 0; s < 4; ++s)
#pragma unroll
                for (int el = 0; el < 5; ++el)
                    a[s][el] = fmaxf(acc[s][el], 0.f);
        } else {
#pragma unroll
            for (int s = 0; s < 4; ++s)
#pragma unroll
                for (int el = 0; el < 5; ++el) {
                    a[s][5 + el] = fmaxf(acc[s][el], 0.f);
                    exch[g][s][el][lane] = a[s][5 + el];
                }
        }
        asm volatile("s_waitcnt lgkmcnt(0)" ::: "memory");
        asm volatile("s_barrier" ::: "memory");

        if (h == 0) {
#pragma unroll
            for (int s = 0; s < 4; ++s)
#pragma unroll
                for (int el = 0; el < 5; ++el)
                    a[s][5 + el] = exch[g][s][el][lane];
            if (l + 1 < NLAYER) {
#pragma unroll
                for (int s = 0; s < 4; ++s)
#pragma unroll
                    for (int el = 0; el < 5; ++el)
                        exch[g][s][el][lane] = a[s][el];
            }
        }
        if (l + 1 < NLAYER) {
            asm volatile("s_waitcnt lgkmcnt(0)" ::: "memory");
            asm volatile("s_barrier" ::: "memory");
            if (h == 1) {
#pragma unroll
                for (int s = 0; s < 4; ++s)
#pragma unroll
                    for (int el = 0; el < 5; ++el)
                        a[s][el] = exch[g][s][el][lane];
            }
        }
    }

    if (h == 0) {
        float wo[DD];
        const float2* p = (const float2*)(Wo + lane * DD);
#pragma unroll
        for (int d2 = 0; d2 < 5; ++d2) {
            float2 v = p[d2];
            wo[d2*2] = v.x; wo[d2*2+1] = v.y;
        }
#pragma unroll
        for (int s = 0; s < 4; ++s) {
            float v = 0.f;
#pragma unroll
            for (int d = 0; d < DD; ++d) v = fmaf(a[s][d], wo[d], v);
            out[(size_t)(b0 + s) * BANKS + lane] = fmaxf(v, 0.f);
        }

#pragma unroll
        for (int s = 0; s < 4; ++s) {
            float v = gsum[s];
#pragma unroll
            for (int off = 32; off; off >>= 1) v += __shfl_xor(v, off, 64);
            if (lane == 0)
                out[(size_t)4096 * BANKS + b0 + s] = v * (1.0f / 7680.0f);
        }
        {
            unsigned int v = nop;
#pragma unroll
            for (int off = 32; off; off >>= 1) v += __shfl_xor(v, off, 64);
            if (lane == 0) atomicAdd(nopen_g, v);
        }
    }
}

// ---------------- Kernel C: finalize scalar ----------------
__global__ void finalize_prob(const unsigned int* __restrict__ nopen,
                              float* __restrict__ out)
{
    out[4096*64 + 4096] = (float)(*nopen) / 31457280.0f;  // /(7680*4096)
}

extern "C" void kernel_launch(void* const* d_in, const int* in_sizes, int n_in,
                              void* d_out, int out_size, void* d_ws, size_t ws_size,
                              hipStream_t stream)
{
    const float* x  = (const float*)d_in[0];
    const float* Wi = (const float*)d_in[1];
    const float* bi = (const float*)d_in[2];
    const float* Wg = (const float*)d_in[3];
    const float* bg = (const float*)d_in[4];
    const float* Wd = (const float*)d_in[5];
    const float* Wo = (const float*)d_in[6];
    float* out = (float*)d_out;

    const size_t ACTS_BYTES  = (size_t)4096 * NBF * 4;          // 10485760
    const size_t CHUNK_BYTES = (size_t)NCH * 16;                //  3440640
    const size_t BIAS_BYTES  = (size_t)NBI * 16;                //    30720
    const size_t FULL_BYTES  = ACTS_BYTES + CHUNK_BYTES + BIAS_BYTES + 64;

    bool full    = ws_size >= FULL_BYTES;
    bool actonly = !full && ws_size >= ACTS_BYTES + 64;

    float* acts0 = (full || actonly) ? (float*)d_ws : nullptr;
    float4* chunk_t = full ? (float4*)((char*)d_ws + ACTS_BYTES) : nullptr;
    float4* bias_t  = full ? (float4*)((char*)d_ws + ACTS_BYTES + CHUNK_BYTES) : nullptr;
    unsigned int* nopen = full
        ? (unsigned int*)((char*)d_ws + ACTS_BYTES + CHUNK_BYTES + BIAS_BYTES)
        : (actonly ? (unsigned int*)((char*)d_ws + ACTS_BYTES)
                   : (unsigned int*)d_ws);

    if (full) {
        fused_prologue<<<GEMM_BLKS + TR_BLKS, 256, 0, stream>>>(
            x, Wi, bi, Wg, bg, Wd, acts0, chunk_t, bias_t, nopen);
        routenet_v13<<<4096 / NSB, 512, 0, stream>>>(
            acts0, chunk_t, bias_t, Wo, out, nopen);
    } else {
        hipMemsetAsync(nopen, 0, 4, stream);
        if (acts0) {
            fused_prologue<<<GEMM_BLKS, 256, 0, stream>>>(
                x, Wi, bi, Wg, bg, Wd, acts0, nullptr, nullptr, nullptr);
        }
        routenet_v5f<<<4096 / NSB, 256, 0, stream>>>(
            acts0, x, Wi, bi, Wg, bg, Wd, Wo, out, nopen);
    }
    finalize_prob<<<1, 1, 0, stream>>>(nopen, out);
}

// Round 14
// 262.335 us; speedup vs baseline: 2.2104x; 2.2104x over previous
//
#include <hip/hip_runtime.h>
#include <type_traits>

#define NIN 784
#define BANKS 64
#define NLAYER 15
#define FAN 8
#define DD 10
#define NBF 640             // features per sample per layer
#define NSW 4               // samples per sample-group (per wave)
#define NSB 8               // samples per block (2 groups x 4)

typedef float f32x2 __attribute__((ext_vector_type(2)));

__device__ __forceinline__ float f4c_rt(const float4& v, int c) {
    return c == 0 ? v.x : (c == 1 ? v.y : (c == 2 ? v.z : v.w));
}

typedef const __attribute__((address_space(1))) void gas_void;
typedef __attribute__((address_space(3))) void las_void;

__device__ __forceinline__ void gll16(const void* g, void* l) {
    __builtin_amdgcn_global_load_lds((gas_void*)g, (las_void*)l, 16, 0, 0);
}

// chunk_t[l][k][r=0..27][bank] float4 (r<25: Wd quads; 25-27: Wg zero-padded)
// bias_t[l][q][bank] float4 = bg[l][bank][4q..4q+3]
#define NCH (NLAYER*FAN*28*64)   // 215040
#define NBI (NLAYER*2*64)        // 1920
#define GEMM_BLKS 640            // 64 M-tiles x 10 N-tiles (64x64)
#define TR_BLKS   848            // ceil((NCH+NBI)/256)

// ---------------- Fused prologue: input GEMM + weight transpose + nopen zero ----------------
__global__ __launch_bounds__(256)
void fused_prologue(const float* __restrict__ x, const float* __restrict__ Wi,
                    const float* __restrict__ bi,
                    const float* __restrict__ Wg, const float* __restrict__ bg,
                    const float* __restrict__ Wd,
                    float* __restrict__ acts,
                    float4* __restrict__ chunk_t, float4* __restrict__ bias_t,
                    unsigned int* __restrict__ nopen)
{
    if (blockIdx.x >= GEMM_BLKS) {
        if (blockIdx.x == GEMM_BLKS && threadIdx.x == 0 && nopen) *nopen = 0u;
        int tid = (blockIdx.x - GEMM_BLKS) * 256 + threadIdx.x;
        if (tid < NCH) {
            int b = tid & 63;
            int rk = tid >> 6;
            int r = rk % 28;
            int lk = rk / 28;           // l*8+k
            int k = lk & 7;
            int l = lk >> 3;
            float4 v;
            if (r < 25) {
                v = ((const float4*)Wd)[(((size_t)(l*64+b)*8 + k)*25) + r];
            } else {
                int q = r - 25;
                size_t base = ((size_t)(l*64+b)*8 + k)*10 + 4*q;
                float t[4];
#pragma unroll
                for (int c = 0; c < 4; ++c)
                    t[c] = (4*q + c < 10) ? Wg[base + c] : 0.f;
                v = make_float4(t[0], t[1], t[2], t[3]);
            }
            chunk_t[tid] = v;
        } else if (tid < NCH + NBI) {
            int t2 = tid - NCH;
            int b = t2 & 63;
            int q = (t2 >> 6) & 1;
            int l = t2 >> 7;
            bias_t[t2] = ((const float4*)bg)[(size_t)(l*64+b)*2 + q];
        }
        return;
    }

    // ---- GEMM part: 64x64 tile, 256 threads, 4x4 per thread ----
    __shared__ float As[16][68];
    __shared__ float Bs[16][68];
    const int tid = threadIdx.x;
    const int tx = tid & 15, ty = tid >> 4;
    const int m0 = (blockIdx.x & 63) * 64;
    const int n0 = (blockIdx.x >> 6) * 64;

    float acc[4][4];
#pragma unroll
    for (int i = 0; i < 4; ++i)
#pragma unroll
        for (int j = 0; j < 4; ++j) acc[i][j] = 0.f;

    for (int kb = 0; kb < NIN / 16; ++kb) {
        {
            int m = tid >> 2, kq = tid & 3;
            float4 v = *(const float4*)(x + (m0 + m) * NIN + kb * 16 + kq * 4);
            As[kq*4+0][m] = v.x; As[kq*4+1][m] = v.y;
            As[kq*4+2][m] = v.z; As[kq*4+3][m] = v.w;
            float4 u = *(const float4*)(Wi + (n0 + m) * NIN + kb * 16 + kq * 4);
            Bs[kq*4+0][m] = u.x; Bs[kq*4+1][m] = u.y;
            Bs[kq*4+2][m] = u.z; Bs[kq*4+3][m] = u.w;
        }
        __syncthreads();
#pragma unroll
        for (int k = 0; k < 16; ++k) {
            float4 a4 = *(const float4*)(&As[k][ty*4]);
            float4 b4 = *(const float4*)(&Bs[k][tx*4]);
            float av[4] = {a4.x, a4.y, a4.z, a4.w};
            float bv[4] = {b4.x, b4.y, b4.z, b4.w};
#pragma unroll
            for (int i = 0; i < 4; ++i)
#pragma unroll
                for (int j = 0; j < 4; ++j)
                    acc[i][j] = fmaf(av[i], bv[j], acc[i][j]);
        }
        __syncthreads();
    }
    float4 bv = *(const float4*)(bi + n0 + tx*4);
#pragma unroll
    for (int i = 0; i < 4; ++i) {
        int row = m0 + ty*4 + i;
        float4 o;
        o.x = fmaxf(acc[i][0] + bv.x, 0.f);
        o.y = fmaxf(acc[i][1] + bv.y, 0.f);
        o.z = fmaxf(acc[i][2] + bv.z, 0.f);
        o.w = fmaxf(acc[i][3] + bv.w, 0.f);
        *(float4*)(acts + row * NBF + n0 + tx*4) = o;
    }
}

// ---------------- Kernel B (v9 exact): v5 structure + pk-FMA packing ----------------
// Proven best routenet: 222 us, WRITE ~27MB, VGPR 128, 2 blocks/CU.
__global__ __launch_bounds__(256, 2)
void routenet_v9(const float* __restrict__ acts0,
                 const float4* __restrict__ chunk_t, const float4* __restrict__ bias_t,
                 const float* __restrict__ Wo,
                 float* __restrict__ out, unsigned int* __restrict__ nopen_g)
{
    __shared__ float4 wdstage[2][28][64];  // 57344 B (rows 0-24 Wd, 25-27 Wg)
    __shared__ float4 biasbuf[2][2][64];   //  4096 B [layer parity][q][bank]
    __shared__ float  exch[2][NSW][5][64]; // 10240 B [g][s][el][bank]

    const int tid  = threadIdx.x;
    const int lane = tid & 63;
    const int w    = tid >> 6;
    const int g    = w & 1;
    const int h    = w >> 1;
    const int b0   = blockIdx.x * NSB + g * NSW;

    // packed activations: A2[p][d] = {a(2p)[d], a(2p+1)[d]}
    f32x2 A2[2][DD];
#pragma unroll
    for (int p = 0; p < 2; ++p) {
        const float2* q0 = (const float2*)(acts0 + (size_t)(b0 + 2*p    ) * NBF + lane * DD);
        const float2* q1 = (const float2*)(acts0 + (size_t)(b0 + 2*p + 1) * NBF + lane * DD);
#pragma unroll
        for (int d2 = 0; d2 < 5; ++d2) {
            float2 v0 = q0[d2], v1 = q1[d2];
            A2[p][2*d2  ] = f32x2{v0.x, v1.x};
            A2[p][2*d2+1] = f32x2{v0.y, v1.y};
        }
    }

    f32x2 gs2[2] = { f32x2{0.f,0.f}, f32x2{0.f,0.f} };
    unsigned int nop = 0;

    auto stage_chunk = [&](int l, int k, int pdst) {
        const float4* base = chunk_t + (size_t)(l*8 + k) * 28 * 64;
#pragma unroll
        for (int j = 0; j < 7; ++j) {
            int r = w + 4 * j;
            gll16(base + r*64 + lane, &wdstage[pdst][r][0]);
        }
    };
    auto stage_bias = [&](int l) {
        int q = w & 1;   // waves 0,2 -> q0; 1,3 -> q1 (duplicate, idempotent)
        gll16(bias_t + (size_t)(l*2 + q)*64 + lane, &biasbuf[l & 1][q][0]);
    };

    stage_chunk(0, 0, 0);
    stage_bias(0);
    asm volatile("s_waitcnt vmcnt(0)" ::: "memory");
    asm volatile("s_barrier" ::: "memory");

    for (int l = 0; l < NLAYER; ++l) {
        const int lp = l & 1;
        f32x2 acc2[2][5];
#pragma unroll
        for (int p = 0; p < 2; ++p)
#pragma unroll
            for (int el = 0; el < 5; ++el) acc2[p][el] = f32x2{0.f, 0.f};

        auto chunk_body = [&](auto Hc, int k, int p) {
            constexpr int H = Hc.value;
            float4 wgq[3];
#pragma unroll
            for (int q = 0; q < 3; ++q) wgq[q] = wdstage[p][25 + q][lane];
            const float bias = f4c_rt(biasbuf[lp][(k >> 2) & 1][lane], k & 3);
            float wgv[DD];
#pragma unroll
            for (int d = 0; d < DD; ++d) wgv[d] = f4c_rt(wgq[d >> 2], d & 3);

            f32x2 gz[2];
#pragma unroll
            for (int pp = 0; pp < 2; ++pp) {
                f32x2 z = f32x2{bias, bias};
#pragma unroll
                for (int d = 0; d < DD; ++d)
                    z = __builtin_elementwise_fma(A2[pp][d], f32x2{wgv[d], wgv[d]}, z);
                f32x2 gate = __builtin_elementwise_min(
                                 __builtin_elementwise_max(z, f32x2{0.f, 0.f}),
                                 f32x2{1.f, 1.f});
                if (H == 0) {
                    gs2[pp] += gate;
                    nop += (z[0] > 0.f) ? 1u : 0u;
                    nop += (z[1] > 0.f) ? 1u : 0u;
                }
                gz[pp] = gate;
            }

            float4 wv[13];
#pragma unroll
            for (int i = 0; i < 13; ++i) wv[i] = wdstage[p][12*H + i][lane];

            const int src = (lane - k) & 63;
#pragma unroll
            for (int el = 0; el < 5; ++el) {
#pragma unroll
                for (int pp = 0; pp < 2; ++pp) {
                    f32x2 dot = f32x2{0.f, 0.f};
#pragma unroll
                    for (int d = 0; d < DD; ++d) {
                        const int idx = (5*H + el) * 10 + d - 48*H;
                        const float wd = f4c_rt(wv[idx >> 2], idx & 3);
                        dot = __builtin_elementwise_fma(A2[pp][d], f32x2{wd, wd}, dot);
                    }
                    f32x2 cc = gz[pp] * dot;
                    f32x2 r;
                    r[0] = __shfl(cc[0], src, 64);
                    r[1] = __shfl(cc[1], src, 64);
                    acc2[pp][el] += r;
                }
            }
        };

#pragma unroll
        for (int c = 0; c < 8; ++c) {
            const int p = c & 1;
            if (c < 7) {
                stage_chunk(l, c + 1, p ^ 1);
                asm volatile("s_waitcnt vmcnt(7)" ::: "memory");
            } else if (l + 1 < NLAYER) {
                stage_chunk(l + 1, 0, p ^ 1);
                stage_bias(l + 1);
                asm volatile("s_waitcnt vmcnt(8)" ::: "memory");
            } else {
                asm volatile("s_waitcnt vmcnt(0)" ::: "memory");
            }
            asm volatile("s_barrier" ::: "memory");

            if (h == 0) chunk_body(std::integral_constant<int,0>{}, c, p);
            else        chunk_body(std::integral_constant<int,1>{}, c, p);

            if (c < 7) {
                asm volatile("s_waitcnt lgkmcnt(0)" ::: "memory");
                asm volatile("s_barrier" ::: "memory");
            }
        }

        // ReLU own half; phase A: h=1 publishes its half (d=5..9)
        if (h == 0) {
#pragma unroll
            for (int s = 0; s < NSW; ++s)
#pragma unroll
                for (int el = 0; el < 5; ++el)
                    A2[s>>1][el][s&1] = fmaxf(acc2[s>>1][el][s&1], 0.f);
        } else {
#pragma unroll
            for (int s = 0; s < NSW; ++s)
#pragma unroll
                for (int el = 0; el < 5; ++el) {
                    float v = fmaxf(acc2[s>>1][el][s&1], 0.f);
                    A2[s>>1][5 + el][s&1] = v;
                    exch[g][s][el][lane] = v;
                }
        }
        asm volatile("s_waitcnt lgkmcnt(0)" ::: "memory");
        asm volatile("s_barrier" ::: "memory");

        if (h == 0) {
#pragma unroll
            for (int s = 0; s < NSW; ++s)
#pragma unroll
                for (int el = 0; el < 5; ++el)
                    A2[s>>1][5 + el][s&1] = exch[g][s][el][lane];
            if (l + 1 < NLAYER) {   // phase B: publish d=0..4
#pragma unroll
                for (int s = 0; s < NSW; ++s)
#pragma unroll
                    for (int el = 0; el < 5; ++el)
                        exch[g][s][el][lane] = A2[s>>1][el][s&1];
            }
        }
        if (l + 1 < NLAYER) {
            asm volatile("s_waitcnt lgkmcnt(0)" ::: "memory");
            asm volatile("s_barrier" ::: "memory");
            if (h == 1) {
#pragma unroll
                for (int s = 0; s < NSW; ++s)
#pragma unroll
                    for (int el = 0; el < 5; ++el)
                        A2[s>>1][el][s&1] = exch[g][s][el][lane];
            }
        }
    }

    // epilogue (h=0 waves have full activations)
    if (h == 0) {
        float wo[DD];
        const float2* pw = (const float2*)(Wo + lane * DD);
#pragma unroll
        for (int d2 = 0; d2 < 5; ++d2) {
            float2 v = pw[d2];
            wo[2*d2] = v.x; wo[2*d2+1] = v.y;
        }
#pragma unroll
        for (int p = 0; p < 2; ++p) {
            f32x2 o = f32x2{0.f, 0.f};
#pragma unroll
            for (int d = 0; d < DD; ++d)
                o = __builtin_elementwise_fma(A2[p][d], f32x2{wo[d], wo[d]}, o);
            out[(size_t)(b0 + 2*p    ) * BANKS + lane] = fmaxf(o[0], 0.f);
            out[(size_t)(b0 + 2*p + 1) * BANKS + lane] = fmaxf(o[1], 0.f);
        }

#pragma unroll
        for (int s = 0; s < NSW; ++s) {
            float v = gs2[s>>1][s&1];
#pragma unroll
            for (int off = 32; off; off >>= 1) v += __shfl_xor(v, off, 64);
            if (lane == 0)
                out[(size_t)4096 * BANKS + b0 + s] = v * (1.0f / 7680.0f);
        }
        {
            unsigned int v = nop;
#pragma unroll
            for (int off = 32; off; off >>= 1) v += __shfl_xor(v, off, 64);
            if (lane == 0) atomicAdd(nopen_g, v);
        }
    }
}

// ---------------- Fallback kernel (no-workspace path): v5-style LDS staging ----------------
__global__ __launch_bounds__(256, 2)
void routenet_v5f(const float* __restrict__ acts0,
                  const float* __restrict__ x, const float* __restrict__ Wi,
                  const float* __restrict__ bi,
                  const float* __restrict__ Wg, const float* __restrict__ bg,
                  const float* __restrict__ Wd, const float* __restrict__ Wo,
                  float* __restrict__ out, unsigned int* __restrict__ nopen_g)
{
    __shared__ float4 wdstage[2][28][64];
    __shared__ float4 biasbuf[2][2][64];
    __shared__ float  exch[2][4][5][64];

    const int tid  = threadIdx.x;
    const int lane = tid & 63;
    const int w    = tid >> 6;
    const int g    = w & 1;
    const int h    = w >> 1;
    const int b0   = blockIdx.x * NSB + g * 4;

    float a[4][DD];

    if (acts0) {
#pragma unroll
        for (int s = 0; s < 4; ++s) {
            const float2* p = (const float2*)(acts0 + (size_t)(b0 + s) * NBF + lane * DD);
#pragma unroll
            for (int d2 = 0; d2 < 5; ++d2) {
                float2 v = p[d2];
                a[s][d2*2]   = v.x;
                a[s][d2*2+1] = v.y;
            }
        }
    } else {
        for (int s = 0; s < 4; ++s) {
            const float* xb2 = x + (size_t)(b0 + s) * NIN;
            for (int d = 0; d < DD; ++d) {
                int n = lane * DD + d;
                const float* wr = Wi + (size_t)n * NIN;
                float z = bi[n];
                for (int i = 0; i < NIN; ++i) z = fmaf(xb2[i], wr[i], z);
                a[s][d] = fmaxf(z, 0.f);
            }
        }
    }

    float gsum[4];
#pragma unroll
    for (int s = 0; s < 4; ++s) gsum[s] = 0.f;
    unsigned int nop = 0;

    auto stage_chunk = [&](int l, int k, int pdst) {
        const float* wd_base = Wd + (size_t)l * (BANKS*FAN*DD*DD)
                                  + (size_t)lane * (FAN*DD*DD) + k * (DD*DD);
        const float* wg_base = Wg + (size_t)l * (BANKS*FAN*DD)
                                  + lane * (FAN*DD) + ((10*k) >> 2) * 4;
#pragma unroll
        for (int j = 0; j < 7; ++j) {
            int r = w + 4 * j;
            if (r < 25) gll16(wd_base + r * 4, &wdstage[pdst][r][0]);
            else        gll16(wg_base + (r - 25) * 4, &wdstage[pdst][r][0]);
        }
    };
    auto stage_bias = [&](int l) {
        int q = w & 1;
        gll16(bg + (size_t)l * (BANKS*FAN) + lane * FAN + q * 4,
              &biasbuf[l & 1][q][0]);
    };

    stage_chunk(0, 0, 0);
    stage_bias(0);
    asm volatile("s_waitcnt vmcnt(0)" ::: "memory");
    asm volatile("s_barrier" ::: "memory");

    for (int l = 0; l < NLAYER; ++l) {
        const int lp = l & 1;
        float acc[4][5];
#pragma unroll
        for (int s = 0; s < 4; ++s)
#pragma unroll
            for (int el = 0; el < 5; ++el) acc[s][el] = 0.f;

        auto chunk_body = [&](auto Hc, int k, int p) {
            constexpr int H = Hc.value;
            float4 wgq[3];
#pragma unroll
            for (int q = 0; q < 3; ++q) wgq[q] = wdstage[p][25 + q][lane];
            const float bias = f4c_rt(biasbuf[lp][(k >> 2) & 1][lane], k & 3);
            float wgv[DD];
            if ((k & 1) == 0) {
#pragma unroll
                for (int d = 0; d < DD; ++d) wgv[d] = f4c_rt(wgq[d >> 2], d & 3);
            } else {
#pragma unroll
                for (int d = 0; d < DD; ++d) wgv[d] = f4c_rt(wgq[(d+2) >> 2], (d+2) & 3);
            }

            float gz[4];
#pragma unroll
            for (int s = 0; s < 4; ++s) {
                float z = bias;
#pragma unroll
                for (int d = 0; d < DD; ++d) z = fmaf(a[s][d], wgv[d], z);
                float gate = fminf(fmaxf(z, 0.f), 1.f);
                if (H == 0) { gsum[s] += gate; nop += (z > 0.f) ? 1u : 0u; }
                gz[s] = gate;
            }

            float4 wv[13];
#pragma unroll
            for (int i = 0; i < 13; ++i) wv[i] = wdstage[p][12*H + i][lane];

            const int src = (lane - k) & 63;
#pragma unroll
            for (int el = 0; el < 5; ++el) {
#pragma unroll
                for (int s = 0; s < 4; ++s) {
                    float dot = 0.f;
#pragma unroll
                    for (int d = 0; d < DD; ++d) {
                        const int idx = (5*H + el) * 10 + d - 48*H;
                        dot = fmaf(a[s][d], f4c_rt(wv[idx >> 2], idx & 3), dot);
                    }
                    acc[s][el] += __shfl(gz[s] * dot, src, 64);
                }
            }
        };

#pragma unroll
        for (int c = 0; c < 8; ++c) {
            const int p = c & 1;
            if (c < 7) {
                stage_chunk(l, c + 1, p ^ 1);
                asm volatile("s_waitcnt vmcnt(7)" ::: "memory");
            } else if (l + 1 < NLAYER) {
                stage_chunk(l + 1, 0, p ^ 1);
                stage_bias(l + 1);
                asm volatile("s_waitcnt vmcnt(8)" ::: "memory");
            } else {
                asm volatile("s_waitcnt vmcnt(0)" ::: "memory");
            }
            asm volatile("s_barrier" ::: "memory");

            if (h == 0) chunk_body(std::integral_constant<int,0>{}, c, p);
            else        chunk_body(std::integral_constant<int,1>{}, c, p);

            if (c < 7) {
                asm volatile("s_waitcnt lgkmcnt(0)" ::: "memory");
                asm volatile("s_barrier" ::: "memory");
            }
        }

        if (h == 0) {
#pragma unroll
            for (int s = 0; s < 4; ++s)
#pragma unroll
                for (int el = 0; el < 5; ++el)
                    a[s][el] = fmaxf(acc[s][el], 0.f);
        } else {
#pragma unroll
            for (int s = 0; s < 4; ++s)
#pragma unroll
                for (int el = 0; el < 5; ++el) {
                    a[s][5 + el] = fmaxf(acc[s][el], 0.f);
                    exch[g][s][el][lane] = a[s][5 + el];
                }
        }
        asm volatile("s_waitcnt lgkmcnt(0)" ::: "memory");
        asm volatile("s_barrier" ::: "memory");

        if (h == 0) {
#pragma unroll
            for (int s = 0; s < 4; ++s)
#pragma unroll
                for (int el = 0; el < 5; ++el)
                    a[s][5 + el] = exch[g][s][el][lane];
            if (l + 1 < NLAYER) {
#pragma unroll
                for (int s = 0; s < 4; ++s)
#pragma unroll
                    for (int el = 0; el < 5; ++el)
                        exch[g][s][el][lane] = a[s][el];
            }
        }
        if (l + 1 < NLAYER) {
            asm volatile("s_waitcnt lgkmcnt(0)" ::: "memory");
            asm volatile("s_barrier" ::: "memory");
            if (h == 1) {
#pragma unroll
                for (int s = 0; s < 4; ++s)
#pragma unroll
                    for (int el = 0; el < 5; ++el)
                        a[s][el] = exch[g][s][el][lane];
            }
        }
    }

    if (h == 0) {
        float wo[DD];
        const float2* p = (const float2*)(Wo + lane * DD);
#pragma unroll
        for (int d2 = 0; d2 < 5; ++d2) {
            float2 v = p[d2];
            wo[d2*2] = v.x; wo[d2*2+1] = v.y;
        }
#pragma unroll
        for (int s = 0; s < 4; ++s) {
            float v = 0.f;
#pragma unroll
            for (int d = 0; d < DD; ++d) v = fmaf(a[s][d], wo[d], v);
            out[(size_t)(b0 + s) * BANKS + lane] = fmaxf(v, 0.f);
        }

#pragma unroll
        for (int s = 0; s < 4; ++s) {
            float v = gsum[s];
#pragma unroll
            for (int off = 32; off; off >>= 1) v += __shfl_xor(v, off, 64);
            if (lane == 0)
                out[(size_t)4096 * BANKS + b0 + s] = v * (1.0f / 7680.0f);
        }
        {
            unsigned int v = nop;
#pragma unroll
            for (int off = 32; off; off >>= 1) v += __shfl_xor(v, off, 64);
            if (lane == 0) atomicAdd(nopen_g, v);
        }
    }
}

// ---------------- Kernel C: finalize scalar ----------------
__global__ void finalize_prob(const unsigned int* __restrict__ nopen,
                              float* __restrict__ out)
{
    out[4096*64 + 4096] = (float)(*nopen) / 31457280.0f;  // /(7680*4096)
}

extern "C" void kernel_launch(void* const* d_in, const int* in_sizes, int n_in,
                              void* d_out, int out_size, void* d_ws, size_t ws_size,
                              hipStream_t stream)
{
    const float* x  = (const float*)d_in[0];
    const float* Wi = (const float*)d_in[1];
    const float* bi = (const float*)d_in[2];
    const float* Wg = (const float*)d_in[3];
    const float* bg = (const float*)d_in[4];
    const float* Wd = (const float*)d_in[5];
    const float* Wo = (const float*)d_in[6];
    float* out = (float*)d_out;

    const size_t ACTS_BYTES  = (size_t)4096 * NBF * 4;          // 10485760
    const size_t CHUNK_BYTES = (size_t)NCH * 16;                //  3440640
    const size_t BIAS_BYTES  = (size_t)NBI * 16;                //    30720
    const size_t FULL_BYTES  = ACTS_BYTES + CHUNK_BYTES + BIAS_BYTES + 64;

    bool full    = ws_size >= FULL_BYTES;
    bool actonly = !full && ws_size >= ACTS_BYTES + 64;

    float* acts0 = (full || actonly) ? (float*)d_ws : nullptr;
    float4* chunk_t = full ? (float4*)((char*)d_ws + ACTS_BYTES) : nullptr;
    float4* bias_t  = full ? (float4*)((char*)d_ws + ACTS_BYTES + CHUNK_BYTES) : nullptr;
    unsigned int* nopen = full
        ? (unsigned int*)((char*)d_ws + ACTS_BYTES + CHUNK_BYTES + BIAS_BYTES)
        : (actonly ? (unsigned int*)((char*)d_ws + ACTS_BYTES)
                   : (unsigned int*)d_ws);

    if (full) {
        fused_prologue<<<GEMM_BLKS + TR_BLKS, 256, 0, stream>>>(
            x, Wi, bi, Wg, bg, Wd, acts0, chunk_t, bias_t, nopen);
        routenet_v9<<<4096 / NSB, 256, 0, stream>>>(
            acts0, chunk_t, bias_t, Wo, out, nopen);
    } else {
        hipMemsetAsync(nopen, 0, 4, stream);
        if (acts0) {
            fused_prologue<<<GEMM_BLKS, 256, 0, stream>>>(
                x, Wi, bi, Wg, bg, Wd, acts0, nullptr, nullptr, nullptr);
        }
        routenet_v5f<<<4096 / NSB, 256, 0, stream>>>(
            acts0, x, Wi, bi, Wg, bg, Wd, Wo, out, nopen);
    }
    finalize_prob<<<1, 1, 0, stream>>>(nopen, out);
}